// Round 17
// baseline (97.456 us; speedup 1.0000x reference)
//
#include <hip/hip_runtime.h>
#include <hip/hip_bf16.h>

typedef __attribute__((ext_vector_type(4))) float  f32x4;
typedef __attribute__((ext_vector_type(8))) short  bf16x8;
typedef __attribute__((ext_vector_type(4))) short  bf16x4;

#define DIM       256
#define NBLOCKS   512
#define NTHREADS  512
#define TOKPB     512          // tokens per block
#define NROUNDS   16           // 32-token rounds
#define CBASE     32768        // C-buf: 32 rows x 1 KB fp32 at [32K,64K)
#define LDS_BYTES 65536        // W chunk 32K (startup) -> A 2x16K; C 32K

#define WAITV(N) asm volatile("s_waitcnt vmcnt(" #N ")" ::: "memory")

__device__ __forceinline__ short f2bf(float x) {
    __hip_bfloat16 h = __float2bfloat16(x);
    return *reinterpret_cast<short*>(&h);
}

// Pinned-issue load; vmcnt retires FIFO (m135), so counted waits are exact.
__device__ __forceinline__ f32x4 gload4(const float* p) {
    f32x4 r;
    asm volatile("global_load_dwordx4 %0, %1, off" : "=v"(r) : "v"(p) : "memory");
    return r;
}

// out[n][o] = sum_k X[n][k] * W0[o][k]  (router is degenerate: expert 0 always)
__global__ __launch_bounds__(NTHREADS, 2)   // 256-VGPR cap; demand ~100 -> no spills
void moe_expert0_kernel(const float* __restrict__ X,
                        const float* __restrict__ W0,
                        float* __restrict__ Out)
{
    extern __shared__ char lds[];
    const int tid  = threadIdx.x;
    const int lane = tid & 63;
    const int wave = tid >> 6;
    const int b    = blockIdx.x;

    const int l15 = lane & 15;
    const int lg  = lane >> 4;     // k-subgroup 0..3
    const int cg  = wave & 3;      // 64-chan group 0..3
    const int tg  = wave >> 2;     // 16-token half 0..1 of each 32-token round

    // ---- W in 4 sequential 32-KB chunks (rows c*64..c*64+63), bf16 swizzled:
    // lrow*512 + (cb ^ ((lrow&15)<<4)). Waves with cg==c pull Breg after chunk c.
    bf16x8 Breg[4][8];
    #pragma unroll
    for (int c = 0; c < 4; ++c) {
        #pragma unroll
        for (int i = 0; i < 4; ++i) {
            int chunk = tid + i * NTHREADS;   // 2048 chunks of 8 floats
            int lrow  = chunk >> 5;           // 0..63
            int c8    = chunk & 31;
            const f32x4* src = reinterpret_cast<const f32x4*>(
                W0 + (size_t)(c * 64 + lrow) * DIM + c8 * 8);
            f32x4 f0 = src[0], f1 = src[1];
            bf16x8 w;
            w[0] = f2bf(f0[0]); w[1] = f2bf(f0[1]); w[2] = f2bf(f0[2]); w[3] = f2bf(f0[3]);
            w[4] = f2bf(f1[0]); w[5] = f2bf(f1[1]); w[6] = f2bf(f1[2]); w[7] = f2bf(f1[3]);
            int addr = lrow * 512 + ((c8 * 16) ^ ((lrow & 15) << 4));
            *reinterpret_cast<bf16x8*>(lds + addr) = w;
        }
        asm volatile("s_waitcnt vmcnt(0) lgkmcnt(0)" ::: "memory");
        __builtin_amdgcn_s_barrier();        // chunk c visible
        if (cg == c) {
            #pragma unroll
            for (int nt = 0; nt < 4; ++nt)
                #pragma unroll
                for (int s = 0; s < 8; ++s)
                    Breg[nt][s] = *reinterpret_cast<const bf16x8*>(
                        lds + (nt * 16 + l15) * 512 + ((s * 64 + lg * 16) ^ (l15 << 4)));
            asm volatile("s_waitcnt lgkmcnt(0)" ::: "memory");
        }
        __builtin_amdgcn_s_barrier();        // readers done before overwrite
    }
    // W region dead: A-bufs overlay [0,32K), C-buf at [32K,64K).

    // A-stage: wave burst-loads rows srow4..srow4+3, one 1-KB inst per row.
    const int srow4 = wave * 4;
    const float* Xblk = X + (size_t)b * TOKPB * DIM;
    float*       Oblk = Out + (size_t)b * TOKPB * DIM;

    f32x4 Xrow[4];
    #define ALOAD(R) do {                                                      \
        int rr_ = (R) > NROUNDS - 1 ? NROUNDS - 1 : (R);                       \
        _Pragma("unroll")                                                      \
        for (int jj = 0; jj < 4; ++jj)                                         \
            Xrow[jj] = gload4(Xblk + (size_t)(rr_ * 32 + srow4 + jj) * DIM     \
                              + lane * 4);                                     \
    } while (0)
    #define ASTORE(BUF) do {                                                   \
        _Pragma("unroll")                                                      \
        for (int jj = 0; jj < 4; ++jj) {                                       \
            int row_ = srow4 + jj;                                             \
            f32x4 xv = Xrow[jj];                                               \
            bf16x4 xw;                                                         \
            xw[0] = f2bf(xv[0]); xw[1] = f2bf(xv[1]);                          \
            xw[2] = f2bf(xv[2]); xw[3] = f2bf(xv[3]);                          \
            int dst = (BUF) * 16384 + row_ * 512                               \
                    + ((((lane >> 1) ^ (row_ & 15)) << 4)) + (lane & 1) * 8;   \
            *reinterpret_cast<bf16x4*>(lds + dst) = xw;                        \
        }                                                                      \
    } while (0)

    // prologue: A(0) staged into buf0, loads(1) in flight
    ALOAD(0);
    WAITV(0); __builtin_amdgcn_sched_barrier(0);
    ASTORE(0);
    ALOAD(1);
    asm volatile("s_waitcnt lgkmcnt(0)" ::: "memory");
    __builtin_amdgcn_s_barrier();

    for (int r = 0; r < NROUNDS; ++r) {
        const char* ab = lds + (r & 1) * 16384;

        f32x4 acc[4];
        #pragma unroll
        for (int nt = 0; nt < 4; ++nt) acc[nt] = (f32x4)0.0f;

        #pragma unroll
        for (int s = 0; s < 8; ++s) {
            bf16x8 a0 = *reinterpret_cast<const bf16x8*>(
                ab + (tg * 16 + l15) * 512 + ((s * 64 + lg * 16) ^ (l15 << 4)));
            #pragma unroll
            for (int nt = 0; nt < 4; ++nt)
                acc[nt] = __builtin_amdgcn_mfma_f32_16x16x32_bf16(Breg[nt][s], a0, acc[nt], 0, 0, 0);
        }

        // ds_write acc -> C-buf (16-B slot swizzle, r16-proven):
        // row = tg*16+l15, slot sc = cg*16+nt*4+lg, dst slot = sc ^ (row&7)
        #pragma unroll
        for (int nt = 0; nt < 4; ++nt) {
            int row_ = tg * 16 + l15;
            int sc   = cg * 16 + nt * 4 + lg;
            int dst  = CBASE + row_ * 1024 + ((sc ^ (row_ & 7)) << 4);
            *reinterpret_cast<f32x4*>(lds + dst) = acc[nt];
        }

        if (r + 1 < NROUNDS) {
            // r==0: FIFO holds only 4 loads(1) -> drain. r>=1: FIFO =
            // [4 loads(r+1)][4 burst-stores(r-1)]; vmcnt<=4 => loads retired.
            if (r) { WAITV(4); } else { WAITV(0); }
            __builtin_amdgcn_sched_barrier(0);
            ASTORE((r + 1) & 1);        // consume Xrow BEFORE reloading it (r11)
            ALOAD(r + 2);
        }
        asm volatile("s_waitcnt lgkmcnt(0)" ::: "memory");
        __builtin_amdgcn_s_barrier();   // #1: C(r) complete + A(r+1) visible

        // burst C(r): wave owns rows srow4..srow4+3; ONE contiguous 1-KB nt
        // store per row (fill-kernel shape; r16-proven).
        #pragma unroll
        for (int jj = 0; jj < 4; ++jj) {
            int row_ = srow4 + jj;
            f32x4 v = *reinterpret_cast<const f32x4*>(
                lds + CBASE + row_ * 1024 + ((lane << 4) ^ ((row_ & 7) << 4)));
            __builtin_nontemporal_store(v, reinterpret_cast<f32x4*>(
                Oblk + (size_t)(r * 32 + row_) * DIM + lane * 4));
        }
        asm volatile("" ::: "memory");
        __builtin_amdgcn_s_barrier();   // #2: C-buf free for round r+1
    }
    WAITV(0);   // drain tail prefetches/stores before endpgm
    #undef ALOAD
    #undef ASTORE
}

extern "C" void kernel_launch(void* const* d_in, const int* in_sizes, int n_in,
                              void* d_out, int out_size, void* d_ws, size_t ws_size,
                              hipStream_t stream) {
    (void)in_sizes; (void)n_in; (void)d_ws; (void)ws_size; (void)out_size;
    const float* X = (const float*)d_in[0];
    const float* W = (const float*)d_in[1];   // [8,256,256]; expert 0 = first 65536
    float* Out = (float*)d_out;

    hipFuncSetAttribute((const void*)moe_expert0_kernel,
                        hipFuncAttributeMaxDynamicSharedMemorySize, LDS_BYTES);
    moe_expert0_kernel<<<dim3(NBLOCKS), dim3(NTHREADS), LDS_BYTES, stream>>>(X, W, Out);
}

// Round 18
// 91.744 us; speedup vs baseline: 1.0623x; 1.0623x over previous
//
#include <hip/hip_runtime.h>
#include <hip/hip_bf16.h>

typedef __attribute__((ext_vector_type(4))) float  f32x4;
typedef __attribute__((ext_vector_type(8))) short  bf16x8;
typedef __attribute__((ext_vector_type(4))) short  bf16x4;

#define DIM       256
#define NBLOCKS   256
#define NTHREADS  512
#define NROUNDS   16           // 64-token rounds per block (1024 tokens)
#define CBASE     65536        // C-buf: 64 rows x 1 KB fp32, swizzled 16-B slots
#define LDS_BYTES 131072       // W staging 128K; later: A 2x32K [0,64K) + C 64K

#define WAITV(N) asm volatile("s_waitcnt vmcnt(" #N ")" ::: "memory")

__device__ __forceinline__ short f2bf(float x) {
    __hip_bfloat16 h = __float2bfloat16(x);
    return *reinterpret_cast<short*>(&h);
}

// Pinned-issue load; vmcnt retires FIFO (m135), so counted waits are exact.
__device__ __forceinline__ f32x4 gload4(const float* p) {
    f32x4 r;
    asm volatile("global_load_dwordx4 %0, %1, off" : "=v"(r) : "v"(p) : "memory");
    return r;
}

// System-scope, LLC-no-allocate store: Out is never re-read; keeping it out of
// L2/L3 leaves X fully L3-resident across graph replays (r16 FETCH=132MB was
// Out-stream eviction). Contiguous full-line bursts -> no write amplification.
__device__ __forceinline__ void gstore4_bypass(float* p, f32x4 v) {
    asm volatile("global_store_dwordx4 %0, %1, off sc0 sc1 nt"
                 :: "v"(p), "v"(v) : "memory");
}

// out[n][o] = sum_k X[n][k] * W0[o][k]  (router is degenerate: expert 0 always)
__global__ __launch_bounds__(NTHREADS, 2)   // 256-VGPR cap (round-8 lesson)
void moe_expert0_kernel(const float* __restrict__ X,
                        const float* __restrict__ W0,
                        float* __restrict__ Out)
{
    extern __shared__ char lds[];
    const int tid  = threadIdx.x;
    const int lane = tid & 63;
    const int wave = tid >> 6;
    const int b    = blockIdx.x;

    // ---- stage full W (256x256) -> bf16, XOR-swizzled: row*512 + (cb ^ ((row&15)<<4))
    #pragma unroll
    for (int i = 0; i < 16; ++i) {
        int chunk = tid + i * NTHREADS;   // 8192 chunks of 8 floats
        int row = chunk >> 5;
        int c8  = chunk & 31;
        const f32x4* src = reinterpret_cast<const f32x4*>(W0 + row * DIM + c8 * 8);
        f32x4 f0 = src[0], f1 = src[1];
        bf16x8 w;
        w[0] = f2bf(f0[0]); w[1] = f2bf(f0[1]); w[2] = f2bf(f0[2]); w[3] = f2bf(f0[3]);
        w[4] = f2bf(f1[0]); w[5] = f2bf(f1[1]); w[6] = f2bf(f1[2]); w[7] = f2bf(f1[3]);
        int addr = row * 512 + ((c8 * 16) ^ ((row & 15) << 4));
        *reinterpret_cast<bf16x8*>(lds + addr) = w;
    }
    asm volatile("s_waitcnt vmcnt(0) lgkmcnt(0)" ::: "memory");
    __builtin_amdgcn_s_barrier();          // W visible to all waves

    const int l15 = lane & 15;
    const int lg  = lane >> 4;     // k-subgroup 0..3
    const int cg  = wave & 3;      // 64-chan group 0..3
    const int tg  = wave >> 2;     // 32-token half 0..1 of each 64-token round

    // ---- B into VGPRs once: 4 nt x 8 s x 16 B/lane = 128 VGPR (r12-proven) ----
    bf16x8 Breg[4][8];
    #pragma unroll
    for (int nt = 0; nt < 4; ++nt)
        #pragma unroll
        for (int s = 0; s < 8; ++s)
            Breg[nt][s] = *reinterpret_cast<const bf16x8*>(
                lds + (cg * 64 + nt * 16 + l15) * 512 + ((s * 64 + lg * 16) ^ (l15 << 4)));
    asm volatile("s_waitcnt lgkmcnt(0)" ::: "memory");
    __builtin_amdgcn_s_barrier();          // W region dead: A-bufs overlay [0,64K),
                                           // C-buf lives at [64K,128K)

    // A-stage (round-10 proven): wave burst-loads rows srow..srow+7 (1 KB/inst)
    const int srow = wave * 8;
    const float* Xblk = X + (size_t)b * 1024 * DIM;
    float*       Oblk = Out + (size_t)b * 1024 * DIM;

    f32x4 Xrow[8];
    #define ALOAD(R) do {                                                      \
        int rr_ = (R) > NROUNDS - 1 ? NROUNDS - 1 : (R);                       \
        _Pragma("unroll")                                                      \
        for (int jj = 0; jj < 8; ++jj)                                         \
            Xrow[jj] = gload4(Xblk + (size_t)(rr_ * 64 + srow + jj) * DIM      \
                              + lane * 4);                                     \
    } while (0)
    #define ASTORE(BUF) do {                                                   \
        _Pragma("unroll")                                                      \
        for (int jj = 0; jj < 8; ++jj) {                                       \
            int row_ = srow + jj;                                              \
            f32x4 xv = Xrow[jj];                                               \
            bf16x4 xw;                                                         \
            xw[0] = f2bf(xv[0]); xw[1] = f2bf(xv[1]);                          \
            xw[2] = f2bf(xv[2]); xw[3] = f2bf(xv[3]);                          \
            int dst = (BUF) * 32768 + row_ * 512                               \
                    + ((((lane >> 1) ^ (row_ & 15)) << 4)) + (lane & 1) * 8;   \
            *reinterpret_cast<bf16x4*>(lds + dst) = xw;                        \
        }                                                                      \
    } while (0)

    // prologue: A(0) staged into buf0, loads(1) in flight
    ALOAD(0);
    WAITV(0); __builtin_amdgcn_sched_barrier(0);
    ASTORE(0);
    ALOAD(1);
    asm volatile("s_waitcnt lgkmcnt(0)" ::: "memory");
    __builtin_amdgcn_s_barrier();

    for (int r = 0; r < NROUNDS; ++r) {
        const char* ab = lds + (r & 1) * 32768;

        f32x4 acc[2][4];
        #pragma unroll
        for (int mt = 0; mt < 2; ++mt)
            #pragma unroll
            for (int nt = 0; nt < 4; ++nt) acc[mt][nt] = (f32x4)0.0f;

        #pragma unroll
        for (int s = 0; s < 8; ++s) {
            bf16x8 a0 = *reinterpret_cast<const bf16x8*>(
                ab + (tg * 32 + l15) * 512      + ((s * 64 + lg * 16) ^ (l15 << 4)));
            bf16x8 a1 = *reinterpret_cast<const bf16x8*>(
                ab + (tg * 32 + 16 + l15) * 512 + ((s * 64 + lg * 16) ^ (l15 << 4)));
            #pragma unroll
            for (int nt = 0; nt < 4; ++nt) {
                acc[0][nt] = __builtin_amdgcn_mfma_f32_16x16x32_bf16(Breg[nt][s], a0, acc[0][nt], 0, 0, 0);
                acc[1][nt] = __builtin_amdgcn_mfma_f32_16x16x32_bf16(Breg[nt][s], a1, acc[1][nt], 0, 0, 0);
            }
        }

        // ds_write acc -> C-buf, 16-B slot swizzle (slot = sc ^ (row&7)):
        // token row = tg*32+mt*16+l15, slot sc = cg*16+nt*4+lg (r16-proven).
        #pragma unroll
        for (int mt = 0; mt < 2; ++mt)
            #pragma unroll
            for (int nt = 0; nt < 4; ++nt) {
                int row_ = tg * 32 + mt * 16 + l15;
                int sc   = cg * 16 + nt * 4 + lg;
                int dst  = CBASE + row_ * 1024 + ((sc ^ (row_ & 7)) << 4);
                *reinterpret_cast<f32x4*>(lds + dst) = acc[mt][nt];
            }

        if (r + 1 < NROUNDS) {
            // r==0: FIFO holds only the 8 loads(1) -> drain. r>=1: FIFO =
            // [8 loads(r+1)][8 burst-stores(r-1)]; vmcnt<=8 => oldest 8 =
            // loads retired (r10/12/13/16-proven, store-agnostic).
            if (r) { WAITV(8); } else { WAITV(0); }
            __builtin_amdgcn_sched_barrier(0);
            ASTORE((r + 1) & 1);        // consume Xrow BEFORE reloading it (r11)
            ALOAD(r + 2);
        }
        asm volatile("s_waitcnt lgkmcnt(0)" ::: "memory");
        __builtin_amdgcn_s_barrier();   // #1: C(r) complete + A(r+1) visible

        // burst C(r): wave owns rows srow..srow+7; ONE contiguous 1-KB
        // cache-bypass store per row (fill-kernel shape; r16-proven layout).
        #pragma unroll
        for (int jj = 0; jj < 8; ++jj) {
            int row_ = srow + jj;
            f32x4 v = *reinterpret_cast<const f32x4*>(
                lds + CBASE + row_ * 1024 + ((lane << 4) ^ ((row_ & 7) << 4)));
            gstore4_bypass(Oblk + (size_t)(r * 64 + row_) * DIM + lane * 4, v);
        }
        asm volatile("" ::: "memory");  // pin burst reads/stores before barrier
        __builtin_amdgcn_s_barrier();   // #2: C-buf free for round r+1
    }
    WAITV(0);   // drain tail prefetches/stores before endpgm
    #undef ALOAD
    #undef ASTORE
}

extern "C" void kernel_launch(void* const* d_in, const int* in_sizes, int n_in,
                              void* d_out, int out_size, void* d_ws, size_t ws_size,
                              hipStream_t stream) {
    (void)in_sizes; (void)n_in; (void)d_ws; (void)ws_size; (void)out_size;
    const float* X = (const float*)d_in[0];
    const float* W = (const float*)d_in[1];   // [8,256,256]; expert 0 = first 65536
    float* Out = (float*)d_out;

    hipFuncSetAttribute((const void*)moe_expert0_kernel,
                        hipFuncAttributeMaxDynamicSharedMemorySize, LDS_BYTES);
    moe_expert0_kernel<<<dim3(NBLOCKS), dim3(NTHREADS), LDS_BYTES, stream>>>(X, W, Out);
}